// Round 8
// baseline (116.527 us; speedup 1.0000x reference)
//
#include <hip/hip_runtime.h>
#include <stdint.h>

// Exact k-subset sampler, 4-lanes-per-row layout, zero __syncthreads.
// Wave = 16 rows x 4 lanes. sub = lane&3: p = sub>>1 (sample id / L4-half),
// q = sub&1 (within-sample worker). slot = wave*16 + r indexes LDS columns.
//   Phase A (up, exact OCML): lane owns L3-subtree t = sub (8 leaves ->
//     L1 x4, L2 x2, L3). L4 is output-split by q ({1,2,7,8} vs {3,4,5,6})
//     through a shared runtime loop. Two wave_barriers pin LDS ordering
//     (in-wave DS is in-order; mechanism verified R6-R7).
//   Phase B (down, fast __expf/__logf; feeds marginals only, thr 2e-2):
//     lane owns n3 = t: e3, 2x e2, 4x e1, 8 marginal columns.
//   Phase C (sampling, bit-exact): sample s = p; root argmax split by q
//     (contiguous j ranges, combined with one shfl_xor; lo-wins-ties ==
//     global ascending-j first-max). After root the count flow is lane-local:
//     li1 task q -> li2 {2q,2q+1} -> li3 {4q..4q+3} -> li4 pairs {8q..8q+7}.
//     All skipped draws are infeasible (-1e10 can't win) or argmax-of-one =>
//     bitwise-identical samples (PRNG + pruning verified rounds 1-7).

__host__ __device__ __forceinline__ void tf2x32(uint32_t k0, uint32_t k1,
                                                uint32_t x0, uint32_t x1,
                                                uint32_t& y0, uint32_t& y1) {
  const uint32_t ks[3] = {k0, k1, k0 ^ k1 ^ 0x1BD11BDAu};
  x0 += ks[0]; x1 += ks[1];
  const int R0[4] = {13, 15, 26, 6};
  const int R1[4] = {17, 29, 16, 24};
#pragma unroll
  for (int i = 0; i < 5; ++i) {
    const int* R = (i & 1) ? R1 : R0;
#pragma unroll
    for (int rr = 0; rr < 4; ++rr) {
      x0 += x1;
      x1 = (x1 << R[rr]) | (x1 >> (32 - R[rr]));
      x1 ^= x0;
    }
    x0 += ks[(i + 1) % 3];
    x1 += ks[(i + 2) % 3] + (uint32_t)(i + 1);
  }
  y0 = x0; y1 = x1;
}

struct TFKeys { uint32_t v[10]; };

// Exact gumbel (OCML logf) — must stay bit-identical to JAX reference.
__device__ __forceinline__ float gumbel_draw(uint32_t sk0, uint32_t sk1,
                                             uint32_t f) {
  uint32_t y0, y1;
  tf2x32(sk0, sk1, 0u, f, y0, y1);
  uint32_t bits = y0 ^ y1;
  uint32_t fb = (bits >> 9) | 0x3f800000u;
  float u = __uint_as_float(fb) - 1.0f;
  const float tiny = 1.17549435e-38f;
  float rr = fmaxf(tiny, u + tiny);
  return -logf(-logf(rr));
}

template<bool FAST> __device__ __forceinline__ float expT(float x) {
  return FAST ? __expf(x) : expf(x);
}
template<bool FAST> __device__ __forceinline__ float logT(float x) {
  return FAST ? __logf(x) : logf(x);
}

// o[m] = logsumexp_j aL[j] + aR[m-j] over in-support j, ascending-j sum.
template<int SIN, int SOUT, bool FAST>
__device__ __forceinline__ void conv_level(const float (&aL)[SIN],
                                           const float (&aR)[SIN],
                                           float (&o)[SOUT]) {
#pragma unroll
  for (int m = 1; m < SOUT; ++m) {
    const int jlo = (m - (SIN - 1) > 0) ? (m - (SIN - 1)) : 0;
    const int jhi = (m < SIN - 1) ? m : (SIN - 1);
    float t[SIN];
#pragma unroll
    for (int j = 0; j < SIN; ++j)
      if (j >= jlo && j <= jhi) t[j] = aL[j] + aR[m - j];
    float amax = t[jlo];
#pragma unroll
    for (int j = 0; j < SIN; ++j)
      if (j > jlo && j <= jhi) amax = fmaxf(amax, t[j]);
    float s = 0.0f;
#pragma unroll
    for (int j = 0; j < SIN; ++j)
      if (j >= jlo && j <= jhi) s += expT<FAST>(t[j] - amax);
    o[m] = logT<FAST>(s) + amax;
  }
}

// eo[m] = logsumexp_{j=max(0,m-SSIB+1)..m} ein[j] + sib[m-j]
template<int SSIB, int MLO, int MHI, bool FAST>
__device__ __forceinline__ void ext_level(const float (&ein)[8],
                                          const float* sib, float (&eo)[8]) {
#pragma unroll
  for (int m = MLO; m <= MHI; ++m) {
    const int jlo = (m - (SSIB - 1) > 0) ? (m - (SSIB - 1)) : 0;
    float t[8];
#pragma unroll
    for (int j = 0; j < 8; ++j)
      if (j >= jlo && j <= m) t[j] = ein[j] + sib[m - j];
    float amax = t[jlo];
#pragma unroll
    for (int j = 0; j < 8; ++j)
      if (j > jlo && j <= m) amax = fmaxf(amax, t[j]);
    float s = 0.0f;
#pragma unroll
    for (int j = 0; j < 8; ++j)
      if (j >= jlo && j <= m) s += expT<FAST>(t[j] - amax);
    eo[m] = logT<FAST>(s) + amax;
  }
}

// LDS entry map (padded stride 65 over 64 row-slots; bank = (e+slot)%32 ->
// uniform-entry wave access = 16 banks x 4-lane broadcast = conflict-free):
//  theta col c        : 0..31
//  L1 m=1, node n1    : 32 + n1   (n1 0..15)
//  L1 m=2, node n1    : 48 + n1
//  L2 node n2, m=1..4 : 64 + n2*4 + (m-1)   (n2 0..7)
//  L3 node n3, m=1..8 : 96 + n3*8 + (m-1)   (n3 0..3)
//  L4 node n4, m=1..8 : 128 + n4*8 + (m-1)  (n4 0..1)
#define ENT 144

__global__ __launch_bounds__(256, 4) void simple_sampler_kernel(
    const float* __restrict__ scores, float* __restrict__ out,
    int nnodes, TFKeys keys) {
  const int tid = threadIdx.x;
  const int w = tid >> 6;
  const int lane = tid & 63;
  const int sub = lane & 3;
  const int q = sub & 1;
  const int p = sub >> 1;
  const int r = lane >> 2;           // 0..15
  const int slot = w * 16 + r;       // 0..63
  const int row = blockIdx.x * 64 + slot;
  const int node = row >> 3, e = row & 7;
  const int B = nnodes * 8;
  const int t = sub;                 // owned L3 subtree

  __shared__ float tab[ENT * 65];
#define L(E) tab[(E) * 65 + slot]

  // ---- load own 8 leaves, stash theta ----
  float th[8];
  const float* sc = scores + node * 256 + e + t * 64;
#pragma unroll
  for (int c = 0; c < 8; ++c) th[c] = sc[c * 8];
#pragma unroll
  for (int c = 0; c < 8; ++c) L(8 * t + c) = th[c];

  // ---- up pass: L1 (4 nodes), exact ----
  float l1r[4], th2r[4];
#pragma unroll
  for (int i = 0; i < 4; ++i) {
    float tL = th[2 * i], tR = th[2 * i + 1];
    float amax = fmaxf(tR, tL);              // t0 = thR (j=0), t1 = thL
    float s = expf(tR - amax) + expf(tL - amax);
    l1r[i] = logf(s) + amax;
    th2r[i] = tL + tR;                        // exact: logf(1.0f)==0.0f
    int n1 = 4 * t + i;
    L(32 + n1) = l1r[i];
    L(48 + n1) = th2r[i];
  }
  // ---- L2 (2 nodes) ----
  float l2r[2][5];
#pragma unroll
  for (int i = 0; i < 2; ++i) {
    float aL[3] = {0.0f, l1r[2 * i], th2r[2 * i]};
    float aR[3] = {0.0f, l1r[2 * i + 1], th2r[2 * i + 1]};
    float o5[5];
    conv_level<3, 5, false>(aL, aR, o5);
    l2r[i][0] = 0.0f;
    int n2 = 2 * t + i;
#pragma unroll
    for (int m = 1; m < 5; ++m) { l2r[i][m] = o5[m]; L(64 + n2 * 4 + m - 1) = o5[m]; }
  }
  // ---- L3 (own node t) ----
  {
    float o9[9];
    conv_level<5, 9, false>(l2r[0], l2r[1], o9);
#pragma unroll
    for (int m = 1; m < 9; ++m) L(96 + t * 8 + m - 1) = o9[m];
  }

  __builtin_amdgcn_wave_barrier();   // L3 writes before L4 reads

  // ---- L4 node p, outputs split by q: q0 -> {1,2,7,8}, q1 -> {3,4,5,6} ----
  {
    const int eA = 96 + 16 * p;      // L3[2p] m-base
    const int eB = eA + 8;           // L3[2p+1] m-base
#pragma unroll
    for (int k = 0; k < 4; ++k) {
      int m = q ? (k + 3) : ((k < 2) ? (k + 1) : (k + 5));
      float amax = -3.0e38f;
      for (int j = 0; j <= m; ++j) {
        float a = j ? L(eA + j - 1) : 0.0f;
        int mj = m - j;
        float b = mj ? L(eB + mj - 1) : 0.0f;
        amax = fmaxf(amax, a + b);
      }
      float s = 0.0f;
      for (int j = 0; j <= m; ++j) {
        float a = j ? L(eA + j - 1) : 0.0f;
        int mj = m - j;
        float b = mj ? L(eB + mj - 1) : 0.0f;
        s += expf((a + b) - amax);
      }
      L(128 + 8 * p + m - 1) = logf(s) + amax;
    }
  }

  __builtin_amdgcn_wave_barrier();   // L4 writes before A reads

  // ---- read both L4 tables into regs ----
  float A0[9], A1[9];
  A0[0] = 0.0f; A1[0] = 0.0f;
#pragma unroll
  for (int m = 1; m < 9; ++m) { A0[m] = L(128 + m - 1); A1[m] = L(136 + m - 1); }

  // ---- logZ (marginals only -> fast) ----
  float logZ;
  {
    float tv[9];
#pragma unroll
    for (int j = 0; j < 9; ++j) tv[j] = A0[j] + A1[8 - j];
    float amax = tv[0];
#pragma unroll
    for (int j = 1; j < 9; ++j) amax = fmaxf(amax, tv[j]);
    float s = 0.0f;
#pragma unroll
    for (int j = 0; j < 9; ++j) s += __expf(tv[j] - amax);
    logZ = __logf(s) + amax;
  }

  // ---- down pass, subtree n3 = t (fast path; marginals only) ----
  {
    float e4v[8];
    e4v[0] = 0.0f;
#pragma unroll
    for (int m = 1; m < 8; ++m) e4v[m] = p ? A0[m] : A1[m];  // sibling of n4=p
    float sib3[9];
    sib3[0] = 0.0f;
#pragma unroll
    for (int m = 1; m < 9; ++m) sib3[m] = L(96 + (t ^ 1) * 8 + m - 1);
    float e3[8];
    ext_level<9, 0, 7, true>(e4v, sib3, e3);
    float* mb = out + 2 * B * 32 + node * 256 + e;
#pragma unroll
    for (int i2 = 0; i2 < 2; ++i2) {
      float e2v[8];
      ext_level<5, 4, 7, true>(e3, l2r[i2 ^ 1], e2v);
#pragma unroll
      for (int i1l = 0; i1l < 2; ++i1l) {
        const int i1 = 2 * i2 + i1l;
        float sib1[3] = {0.0f, l1r[i1 ^ 1], th2r[i1 ^ 1]};
        float e1m[8];
        ext_level<3, 6, 7, true>(e2v, sib1, e1m);
        const int colL = 8 * t + 2 * i1;
        {
          float t6 = e1m[6] + th[2 * i1 + 1];
          float t7 = e1m[7];
          float amax = fmaxf(t6, t7);
          float s = __expf(t6 - amax) + __expf(t7 - amax);
          mb[colL * 8] = __expf((th[2 * i1] + (__logf(s) + amax)) - logZ);
        }
        {
          float t6 = e1m[6] + th[2 * i1];
          float t7 = e1m[7];
          float amax = fmaxf(t6, t7);
          float s = __expf(t6 - amax) + __expf(t7 - amax);
          mb[(colL + 1) * 8] = __expf((th[2 * i1 + 1] + (__logf(s) + amax)) - logZ);
        }
      }
    }
  }

  // ---- sampling, sample s = p, worker q (bit-exact path) ----
  const uint32_t t9 = (uint32_t)(p * B + row) * 9u;
  int bj;  // root left count
  {
    float vb = -3.0e38f; int jb = 0;
    const int jbase = q * 5;           // q0: j 0..4, q1: j 5..8
#pragma unroll
    for (int tci = 0; tci < 5; ++tci) {
      int j = jbase + tci;
      if (j <= 8) {
        float g = gumbel_draw(keys.v[0], keys.v[1], t9 + (uint32_t)j);
        float v = (A0[j] + A1[8 - j]) + g;
        if (v > vb) { vb = v; jb = j; }
      }
    }
    float vo = __shfl_xor(vb, 1);
    int jo = __shfl_xor(jb, 1);
    float vlo = q ? vo : vb; int jlo_ = q ? jo : jb;
    float vhi = q ? vb : vo; int jhi_ = q ? jb : jo;
    bj = (vhi > vlo) ? jhi_ : jlo_;    // ties -> lo (smaller j) == first-max
  }
  int cA, cB;
  {  // li1: task q, count c, feasible j = 0..c (all valid; c==0 singleton)
    int c = q ? (8 - bj) : bj;
    int bj1 = 0;
    if (c > 0) {
      float best = -3.0e38f;
      const int eA = 96 + 16 * q, eB = eA + 8;
      for (int j = 0; j <= c; ++j) {
        float a = j ? L(eA + j - 1) : 0.0f;
        int idx = c - j;
        float b = idx ? L(eB + idx - 1) : 0.0f;
        float g = gumbel_draw(keys.v[2], keys.v[3],
                              2u * t9 + (uint32_t)(9 * q + j));
        float v = (a + b) + g;
        if (v > best) { best = v; bj1 = j; }
      }
    }
    cA = bj1; cB = c - bj1;
  }
  int c2o[4];
  {  // li2: tasks 2q, 2q+1; J=5 static with validity
#pragma unroll
    for (int k = 0; k < 2; ++k) {
      const int i2 = 2 * q + k;
      int c = k ? cB : cA;
      float best = -3.0e38f; int bj2 = 0;
#pragma unroll
      for (int j = 0; j < 5; ++j) {
        float g = gumbel_draw(keys.v[4], keys.v[5],
                              4u * t9 + (uint32_t)(i2 * 9 + j));
        int idx = c - j;
        int cl = min(max(idx, 1), 4);
        float b = L(64 + (2 * i2 + 1) * 4 + cl - 1);
        float bf = (idx == 0) ? 0.0f : b;
        float a = (j == 0) ? 0.0f : L(64 + (2 * i2) * 4 + j - 1);
        float v = (a + bf) + g;
        if (idx >= 0 && idx <= 4 && v > best) { best = v; bj2 = j; }
      }
      c2o[2 * k] = bj2; c2o[2 * k + 1] = c - bj2;
    }
  }
  int c3o[8];
  {  // li3: tasks 4q..4q+3; J=3 static with validity
#pragma unroll
    for (int k = 0; k < 4; ++k) {
      const int i3 = 4 * q + k;
      int c = c2o[k];
      float aL1 = L(32 + 2 * i3), aL2 = L(48 + 2 * i3);
      float bR1 = L(32 + 2 * i3 + 1), bR2 = L(48 + 2 * i3 + 1);
      float best = -3.0e38f; int bj3 = 0;
#pragma unroll
      for (int j = 0; j < 3; ++j) {
        float g = gumbel_draw(keys.v[6], keys.v[7],
                              8u * t9 + (uint32_t)(i3 * 9 + j));
        int idx = c - j;
        float bf = (idx == 1) ? bR1 : ((idx == 2) ? bR2 : 0.0f);
        float af = (j == 0) ? 0.0f : ((j == 1) ? aL1 : aL2);
        float v = (af + bf) + g;
        if (idx >= 0 && idx <= 2 && v > best) { best = v; bj3 = j; }
      }
      c3o[2 * k] = bj3; c3o[2 * k + 1] = c - bj3;
    }
  }
  {  // li4: pairs 8q..8q+7; draws only for c==1 (others argmax-of-one)
    const uint32_t sk0 = keys.v[8], sk1 = keys.v[9];
    float* bs = out + p * (B * 32) + node * 256 + e;
    uint32_t lst = 0; int m4 = 0;
#pragma unroll
    for (int k = 0; k < 8; ++k) {
      const int i4 = 8 * q + k;
      int c = c3o[k];
      if (c == 1) {
        lst |= ((uint32_t)k) << (4 * m4);
        ++m4;
      } else {
        int bj4 = c >> 1;                   // 0->0, 2->1
        bs[(2 * i4) * 8] = (float)bj4;
        bs[(2 * i4 + 1) * 8] = (float)(c - bj4);
      }
    }
    for (int tt = 0; tt < m4; ++tt) {
      int k = (int)((lst >> (4 * tt)) & 15u);
      const int i4 = 8 * q + k;
      float thL = L(2 * i4);
      float thR = L(2 * i4 + 1);
      uint32_t fb = 16u * t9 + (uint32_t)(i4 * 9);
      float g0 = gumbel_draw(sk0, sk1, fb);       // j=0: 0 + thR
      float g1 = gumbel_draw(sk0, sk1, fb + 1u);  // j=1: thL + 0
      int bj4 = ((thL + g1) > (thR + g0)) ? 1 : 0;  // first-max: strict >
      bs[(2 * i4) * 8] = (float)bj4;
      bs[(2 * i4 + 1) * 8] = (float)(1 - bj4);
    }
  }
#undef L
}

extern "C" void kernel_launch(void* const* d_in, const int* in_sizes, int n_in,
                              void* d_out, int out_size, void* d_ws, size_t ws_size,
                              hipStream_t stream) {
  const float* scores = (const float*)d_in[0];
  float* out = (float*)d_out;
  const int nnodes = in_sizes[0] / (32 * 8);   // 8192
  const int B = nnodes * 8;                    // 65536 rows

  // key = jax.random.key(42); per level: key, sub = split(key)
  // (partitionable threefry: new = tf(key,(0,0)), sub = tf(key,(0,1)))
  TFKeys K;
  uint32_t k0 = 0u, k1 = 42u;
  for (int t = 0; t < 5; ++t) {
    uint32_t n0, n1, s0, s1;
    tf2x32(k0, k1, 0u, 0u, n0, n1);
    tf2x32(k0, k1, 0u, 1u, s0, s1);
    K.v[2 * t] = s0; K.v[2 * t + 1] = s1;
    k0 = n0; k1 = n1;
  }

  dim3 grid((unsigned)(B / 64)), block(256);
  hipLaunchKernelGGL(simple_sampler_kernel, grid, block, 0, stream,
                     scores, out, nnodes, K);
}